// Round 16
// baseline (195.208 us; speedup 1.0000x reference)
//
#include <hip/hip_runtime.h>

typedef float f16v __attribute__((ext_vector_type(16)));
typedef float f4 __attribute__((ext_vector_type(4)));
typedef float f2 __attribute__((ext_vector_type(2)));

// static_for with FRONTEND-constant indices (SSA, no alloca) — see R6 notes.
template<int I> struct ic { static constexpr int v = I; };
template<int... I> struct iseq {};
template<int N, int... I> struct mk : mk<N-1, N-1, I...> {};
template<int... I> struct mk<0, I...> { using t = iseq<I...>; };
template<class F, int... I>
__device__ __forceinline__ void sfor_impl(F f, iseq<I...>) { (f(ic<I>{}), ...); }
template<int N, class F>
__device__ __forceinline__ void sfor(F f) { sfor_impl(f, typename mk<N>::t{}); }

namespace {
constexpr float kSigma  = 1.2f;    // 2*l2_reg + rho
constexpr float kJitter = 1e-5f;
constexpr int   kIters  = 100;
constexpr int   MD = 16;
constexpr int   ND = 32;
constexpr int   SPA  = 8;    // samples per 128-thread precompute block (16 lanes each)
constexpr int   SPB3 = 32;   // samples per 256-thread iter block (8 lanes each)
constexpr int   SPB  = 8;    // fallback kernel
constexpr int   AS  = 132;
constexpr int   SS  = 36;    // s-slot stride: 8 groups cover all 32 banks once
constexpr int   MIS = 20;
constexpr int   MSS = 328;
}

__device__ __forceinline__ float4 lds_a4(const float* As, int r, int j) {
    return *reinterpret_cast<const float4*>(&As[r * 32 + ((j ^ (r & 7)) << 2)]);
}
__device__ __forceinline__ float lds_a(const float* As, int r, int n) {
    return As[r * 32 + ((((n >> 2) ^ (r & 7)) << 2) | (n & 3))];
}
__device__ __forceinline__ f2 lds_a2(const float* As, int r, int n) {
    return *reinterpret_cast<const f2*>(
        &As[r * 32 + ((((n >> 2) ^ (r & 7)) << 2) | (n & 3))]);
}

// ============================ Kernel A: precompute P, d ============================
// 16 lanes/sample; lane l owns M row l and P rows 2l,2l+1. P stored COLUMN-MAJOR
// per sample for the 8-lane iter kernel: f2 at [gs*1024/2 + n*16 + l] =
// (P[2l][n], P[2l+1][n]). Per column n the 16 lanes write 128B coalesced.
// Iter lane l3 loads f4 at float n*32+4*l3 = column n, rows 4l3..4l3+3 (coalesced).
// NO min-waves bound: R14's (128,3) spilled the ~128-reg live set (65us->252us).
__global__ void __launch_bounds__(128)
precompute_kernel(const float* __restrict__ Ag, const float* __restrict__ bg,
                  const float* __restrict__ cg, float* __restrict__ Pws,
                  float* __restrict__ dws)
{
    __shared__ __align__(16) float A_lds[SPA * AS * 4];
    __shared__ __align__(16) float Mi_lds[SPA * MSS];

    const int t = threadIdx.x;

    {
        const float4* src = reinterpret_cast<const float4*>(Ag) +
                            (size_t)blockIdx.x * (SPA * MD * ND / 4);
        float4* dst = reinterpret_cast<float4*>(A_lds);
        #pragma unroll
        for (int r = 0; r < 8; ++r) {
            int idx = r * 128 + t;
            int smp = idx >> 7;
            int row = (idx >> 3) & 15;
            int j   = idx & 7;
            dst[smp * AS + row * 8 + (j ^ (row & 7))] = src[idx];
        }
    }
    __syncthreads();

    const int lane = t & 63;
    const int l    = lane & 15;
    const int n0   = 2 * l;
    const int smp  = (t >> 6) * 4 + (lane >> 4);
    const size_t gs = (size_t)blockIdx.x * SPA + smp;
    const float* As = &A_lds[smp * AS * 4];
    float* Mi = &Mi_lds[smp * MSS];

    f16v Ar0, Ar1;
    sfor<4>([&](auto J) {
        constexpr int j = decltype(J)::v;
        float4 v  = lds_a4(As, l, j);
        Ar0[4*j+0] = v.x;  Ar0[4*j+1] = v.y;  Ar0[4*j+2] = v.z;  Ar0[4*j+3] = v.w;
        float4 w4 = lds_a4(As, l, j + 4);
        Ar1[4*j+0] = w4.x; Ar1[4*j+1] = w4.y; Ar1[4*j+2] = w4.z; Ar1[4*j+3] = w4.w;
    });

    f16v Mrow, Vrow;
    sfor<16>([&](auto K) {
        constexpr int k = decltype(K)::v;
        float a0 = 0.f, a1 = 0.f, a2 = 0.f, a3 = 0.f;
        sfor<4>([&](auto J) {
            constexpr int j = decltype(J)::v;
            float4 v  = lds_a4(As, k, j);
            a0 += Ar0[4*j+0]*v.x;  a1 += Ar0[4*j+1]*v.y;
            a2 += Ar0[4*j+2]*v.z;  a3 += Ar0[4*j+3]*v.w;
            float4 w4 = lds_a4(As, k, j + 4);
            a0 += Ar1[4*j+0]*w4.x; a1 += Ar1[4*j+1]*w4.y;
            a2 += Ar1[4*j+2]*w4.z; a3 += Ar1[4*j+3]*w4.w;
        });
        Mrow[k] = (a0+a1)+(a2+a3) + ((k == l) ? kJitter : 0.f);
        Vrow[k] = (k == l) ? 1.f : 0.f;
    });

    sfor<16>([&](auto K) {
        constexpr int k = decltype(K)::v;
        float ip = 1.f / __shfl(Mrow[k], k, 16);
        float f  = (l == k) ? 0.f : Mrow[k] * ip;
        sfor<16>([&](auto J) {
            constexpr int j = decltype(J)::v;
            if constexpr (j > k) {
                float mj = __shfl(Mrow[j], k, 16);
                Mrow[j] = (l == k) ? mj * ip : Mrow[j] - f * mj;
            }
        });
        sfor<16>([&](auto J) {
            constexpr int j = decltype(J)::v;
            if constexpr (j < k) {
                float vj = __shfl(Vrow[j], k, 16);
                Vrow[j] = (l == k) ? vj * ip : Vrow[j] - f * vj;
            }
        });
        Vrow[k] = (l == k) ? ip : -f;
    });

    float w = 0.f;
    {
        float bval = bg[gs * MD + l];
        sfor<16>([&](auto K) {
            constexpr int k = decltype(K)::v;
            w += Vrow[k] * __shfl(bval, k, 16);
        });
    }

    sfor<4>([&](auto J) {
        constexpr int j = decltype(J)::v;
        *reinterpret_cast<float4*>(&Mi[l * MIS + 4*j]) =
            make_float4(Vrow[4*j+0], Vrow[4*j+1], Vrow[4*j+2], Vrow[4*j+3]);
    });
    asm volatile("s_waitcnt lgkmcnt(0)" ::: "memory");

    f16v Ca = (f16v)0.0f, Cb = (f16v)0.0f;
    float q0 = 0.f, q1 = 0.f;
    sfor<16>([&](auto K) {
        constexpr int k = decltype(K)::v;
        f2 ak = lds_a2(As, k, n0);
        float wm = __shfl(w, k, 16);
        q0 += ak[0] * wm;
        q1 += ak[1] * wm;
        sfor<4>([&](auto J) {
            constexpr int j = decltype(J)::v;
            float4 mv = *reinterpret_cast<const float4*>(&Mi[k * MIS + 4*j]);
            Ca[4*j+0] += ak[0]*mv.x; Ca[4*j+1] += ak[0]*mv.y;
            Ca[4*j+2] += ak[0]*mv.z; Ca[4*j+3] += ak[0]*mv.w;
            Cb[4*j+0] += ak[1]*mv.x; Cb[4*j+1] += ak[1]*mv.y;
            Cb[4*j+2] += ak[1]*mv.z; Cb[4*j+3] += ak[1]*mv.w;
        });
    });

    f16v P0a = (f16v)0.0f, P0b = (f16v)0.0f;
    f16v P1a = (f16v)0.0f, P1b = (f16v)0.0f;
    sfor<16>([&](auto M) {
        constexpr int m = decltype(M)::v;
        float c0 = Ca[m], c1 = Cb[m];
        sfor<4>([&](auto J) {
            constexpr int j = decltype(J)::v;
            float4 v  = lds_a4(As, m, j);
            P0a[4*j+0] += c0*v.x;  P0a[4*j+1] += c0*v.y;
            P0a[4*j+2] += c0*v.z;  P0a[4*j+3] += c0*v.w;
            P1a[4*j+0] += c1*v.x;  P1a[4*j+1] += c1*v.y;
            P1a[4*j+2] += c1*v.z;  P1a[4*j+3] += c1*v.w;
            float4 w4 = lds_a4(As, m, j + 4);
            P0b[4*j+0] += c0*w4.x; P0b[4*j+1] += c0*w4.y;
            P0b[4*j+2] += c0*w4.z; P0b[4*j+3] += c0*w4.w;
            P1b[4*j+0] += c1*w4.x; P1b[4*j+1] += c1*w4.y;
            P1b[4*j+2] += c1*w4.z; P1b[4*j+3] += c1*w4.w;
        });
    });
    constexpr float is = 1.f / kSigma;
    sfor<16>([&](auto N) {
        constexpr int n = decltype(N)::v;
        P0a[n] = (((n      == n0    ) ? 1.f : 0.f) - P0a[n]) * is;
        P0b[n] = (((n + 16 == n0    ) ? 1.f : 0.f) - P0b[n]) * is;
        P1a[n] = (((n      == n0 + 1) ? 1.f : 0.f) - P1a[n]) * is;
        P1b[n] = (((n + 16 == n0 + 1) ? 1.f : 0.f) - P1b[n]) * is;
    });

    float d0, d1;
    {
        float cv0 = cg[gs * ND + l];
        float cv1 = cg[gs * ND + 16 + l];
        float pc0 = 0.f, pc1 = 0.f;
        sfor<16>([&](auto N) {
            constexpr int n = decltype(N)::v;
            float cn = __shfl(cv0, n, 16);
            pc0 += P0a[n] * cn;
            pc1 += P1a[n] * cn;
        });
        sfor<16>([&](auto N) {
            constexpr int n = decltype(N)::v;
            float cn = __shfl(cv1, n, 16);
            pc0 += P0b[n] * cn;
            pc1 += P1b[n] * cn;
        });
        d0 = q0 - pc0;
        d1 = q1 - pc1;
    }

    {
        // COLUMN-MAJOR store: f2[n*16 + l] = (P[2l][n], P[2l+1][n])
        f2* Pout = reinterpret_cast<f2*>(Pws + gs * (ND * ND));
        sfor<16>([&](auto N) {
            constexpr int n = decltype(N)::v;
            f2 e; e[0] = P0a[n]; e[1] = P1a[n];
            Pout[n * 16 + l] = e;                   // column n
            f2 o; o[0] = P0b[n]; o[1] = P1b[n];
            Pout[(n + 16) * 16 + l] = o;            // column n+16
        });
        f2 dd; dd[0] = d0; dd[1] = d1;
        *reinterpret_cast<f2*>(dws + gs * ND + 2 * l) = dd;
    }
}

// ============================ Kernel B: 100 ADMM iterations ============================
// R9's measured-best form: 8 lanes/sample, 4 vars/lane, column-f4 P fragments,
// plain __builtin_elementwise_fma with splat shufflevector. Scalarizes to
// v_fma_f32 whose splat operand is a DIRECT register read (no movs) — beat the
// asm pk_fma variants (R12: 117, R15: 118) at ~90us. 1KB LDS/sample/iter
// (vs 2KB for 16-lane, whose 95us LDS-return floor capped R10/R15).
__global__ void __launch_bounds__(256)
admm_iter_kernel(const float* __restrict__ Pws, const float* __restrict__ dws,
                 const float* __restrict__ lbg, const float* __restrict__ ubg,
                 float* __restrict__ outg)
{
    __shared__ __align__(16) float S_lds[SPB3 * SS];   // 4608 B

    const int t = threadIdx.x;
    const int lane = t & 63;
    const int l3 = lane & 7;                       // lane within 8-lane group
    const int smp = (t >> 6) * 8 + (lane >> 3);    // sample within block
    const size_t gs = (size_t)blockIdx.x * SPB3 + smp;
    float* Sb = &S_lds[smp * SS];

    // p{n} = column n of P, rows 4l3..4l3+3; coalesced f4 loads
    const f4* Pw = reinterpret_cast<const f4*>(Pws + gs * (ND * ND));
#define PLOAD(n) f4 p##n = Pw[n * 8 + l3];
    PLOAD(0)  PLOAD(1)  PLOAD(2)  PLOAD(3)  PLOAD(4)  PLOAD(5)  PLOAD(6)  PLOAD(7)
    PLOAD(8)  PLOAD(9)  PLOAD(10) PLOAD(11) PLOAD(12) PLOAD(13) PLOAD(14) PLOAD(15)
    PLOAD(16) PLOAD(17) PLOAD(18) PLOAD(19) PLOAD(20) PLOAD(21) PLOAD(22) PLOAD(23)
    PLOAD(24) PLOAD(25) PLOAD(26) PLOAD(27) PLOAD(28) PLOAD(29) PLOAD(30) PLOAD(31)
#undef PLOAD

    f4 dv = *reinterpret_cast<const f4*>(dws + gs * ND + 4 * l3);
    f4 lb = *reinterpret_cast<const f4*>(lbg + gs * ND + 4 * l3);
    f4 ub = *reinterpret_cast<const f4*>(ubg + gs * ND + 4 * l3);
    f4 z  = __builtin_elementwise_min(__builtin_elementwise_max((f4)0.0f, lb), ub);
    f4 u  = (f4)0.0f;
    f4 xv = (f4)0.0f;

    const f4* Sv = reinterpret_cast<const f4*>(Sb);
    for (int it = 0; it < kIters; ++it) {
        *reinterpret_cast<f4*>(&Sb[4 * l3]) = z - u;       // rho == 1
        asm volatile("s_waitcnt lgkmcnt(0)" ::: "memory"); // wave-synchronous exchange
        f4 acc0 = dv;
        f4 acc1 = (f4)0.0f, acc2 = (f4)0.0f, acc3 = (f4)0.0f;
#define QSTEP(q, pa, pb, pc, pd)                                              \
        {                                                                     \
            f4 S4 = Sv[q];            /* uniform per 8-lane group */          \
            acc0 = __builtin_elementwise_fma(pa, __builtin_shufflevector(S4,S4,0,0,0,0), acc0); \
            acc1 = __builtin_elementwise_fma(pb, __builtin_shufflevector(S4,S4,1,1,1,1), acc1); \
            acc2 = __builtin_elementwise_fma(pc, __builtin_shufflevector(S4,S4,2,2,2,2), acc2); \
            acc3 = __builtin_elementwise_fma(pd, __builtin_shufflevector(S4,S4,3,3,3,3), acc3); \
        }
        QSTEP(0, p0,  p1,  p2,  p3)   QSTEP(1, p4,  p5,  p6,  p7)
        QSTEP(2, p8,  p9,  p10, p11)  QSTEP(3, p12, p13, p14, p15)
        QSTEP(4, p16, p17, p18, p19)  QSTEP(5, p20, p21, p22, p23)
        QSTEP(6, p24, p25, p26, p27)  QSTEP(7, p28, p29, p30, p31)
#undef QSTEP
        xv = (acc0 + acc1) + (acc2 + acc3);
        f4 tv = xv + u;
        z = __builtin_elementwise_min(__builtin_elementwise_max(tv, lb), ub);
        u = tv - z;
    }

    *reinterpret_cast<f4*>(outg + gs * ND + 4 * l3) = xv;
}

// ==================== Fallback: single kernel (if ws too small) ====================
__global__ void __launch_bounds__(256)
admm_qp_kernel(const float* __restrict__ Ag, const float* __restrict__ bg,
               const float* __restrict__ cg, const float* __restrict__ lbg,
               const float* __restrict__ ubg, float* __restrict__ outg)
{
    __shared__ __align__(16) float A_lds[SPB * AS * 4];
    __shared__ __align__(16) float S_lds[SPB * SS];

    const int t = threadIdx.x;
    {
        const float4* src = reinterpret_cast<const float4*>(Ag) +
                            (size_t)blockIdx.x * (SPB * MD * ND / 4);
        float4* dst = reinterpret_cast<float4*>(A_lds);
        #pragma unroll
        for (int r = 0; r < 4; ++r) {
            int idx = r * 256 + t;
            int smp = idx >> 7;
            int row = (idx >> 3) & 15;
            int j   = idx & 7;
            dst[smp * AS + row * 8 + (j ^ (row & 7))] = src[idx];
        }
    }
    __syncthreads();

    const int lane = t & 63;
    const int l    = lane & 31;
    const int lr   = l & 15;
    const int smp  = (t >> 6) * 2 + (lane >> 5);
    const size_t gs = (size_t)blockIdx.x * SPB + smp;
    const float* As = &A_lds[smp * AS * 4];
    float* Sb = &S_lds[smp * SS];

    f16v Mrow, Vrow;
    sfor<16>([&](auto K) {
        constexpr int k = decltype(K)::v;
        float a0 = 0.f, a1 = 0.f, a2 = 0.f, a3 = 0.f;
        sfor<8>([&](auto J) {
            constexpr int j = decltype(J)::v;
            float4 va = lds_a4(As, lr, j);
            float4 vb = lds_a4(As, k, j);
            a0 += va.x*vb.x; a1 += va.y*vb.y; a2 += va.z*vb.z; a3 += va.w*vb.w;
        });
        Mrow[k] = (a0+a1)+(a2+a3) + ((k == lr) ? kJitter : 0.f);
        Vrow[k] = (k == lr) ? 1.f : 0.f;
    });
    sfor<16>([&](auto K) {
        constexpr int k = decltype(K)::v;
        float ip = 1.f / __shfl(Mrow[k], k, 32);
        float f  = (lr == k) ? 0.f : Mrow[k] * ip;
        sfor<16>([&](auto J) {
            constexpr int j = decltype(J)::v;
            if constexpr (j > k) {
                float mj = __shfl(Mrow[j], k, 32);
                Mrow[j] = (lr == k) ? mj * ip : Mrow[j] - f * mj;
            }
        });
        sfor<16>([&](auto J) {
            constexpr int j = decltype(J)::v;
            if constexpr (j < k) {
                float vj = __shfl(Vrow[j], k, 32);
                Vrow[j] = (lr == k) ? vj * ip : Vrow[j] - f * vj;
            }
        });
        Vrow[k] = (lr == k) ? ip : -f;
    });
    float w = 0.f;
    {
        float bval = bg[gs * MD + lr];
        sfor<16>([&](auto K) {
            constexpr int k = decltype(K)::v;
            w += Vrow[k] * __shfl(bval, k, 32);
        });
    }
    f16v C = (f16v)0.0f;
    sfor<16>([&](auto K) {
        constexpr int k = decltype(K)::v;
        float a = lds_a(As, k, l);
        sfor<16>([&](auto M) {
            constexpr int m = decltype(M)::v;
            C[m] += a * __shfl(Vrow[m], k, 32);
        });
    });
    f16v Pa = (f16v)0.0f, Pb = (f16v)0.0f;
    sfor<16>([&](auto M) {
        constexpr int m = decltype(M)::v;
        float cm = C[m];
        sfor<4>([&](auto J) {
            constexpr int j = decltype(J)::v;
            float4 v  = lds_a4(As, m, j);
            Pa[4*j+0] += cm*v.x;  Pa[4*j+1] += cm*v.y;
            Pa[4*j+2] += cm*v.z;  Pa[4*j+3] += cm*v.w;
            float4 w4 = lds_a4(As, m, j + 4);
            Pb[4*j+0] += cm*w4.x; Pb[4*j+1] += cm*w4.y;
            Pb[4*j+2] += cm*w4.z; Pb[4*j+3] += cm*w4.w;
        });
    });
    constexpr float is = 1.f / kSigma;
    sfor<16>([&](auto N) {
        constexpr int n = decltype(N)::v;
        Pa[n] = (((n      == l) ? 1.f : 0.f) - Pa[n]) * is;
        Pb[n] = (((n + 16 == l) ? 1.f : 0.f) - Pb[n]) * is;
    });
    float d;
    {
        float q = 0.f;
        sfor<16>([&](auto M) {
            constexpr int m = decltype(M)::v;
            q += lds_a(As, m, l) * __shfl(w, m, 32);
        });
        float cval = cg[gs * ND + l];
        float pc0 = 0.f, pc1 = 0.f;
        sfor<16>([&](auto N) {
            constexpr int n = decltype(N)::v;
            pc0 += Pa[n] * __shfl(cval, n,      32);
            pc1 += Pb[n] * __shfl(cval, n + 16, 32);
        });
        d = q - (pc0 + pc1);
    }
    float lb = lbg[gs * ND + l];
    float ub = ubg[gs * ND + l];
    float z  = fminf(fmaxf(0.f, lb), ub);
    float u  = 0.f, x = 0.f;
    for (int it = 0; it < kIters; ++it) {
        Sb[l] = z - u;
        asm volatile("s_waitcnt lgkmcnt(0)" ::: "memory");
        float a0 = d, a1 = 0.f, a2 = 0.f, a3 = 0.f;
        sfor<4>([&](auto K) {
            constexpr int k = decltype(K)::v;
            float4 sA = *reinterpret_cast<const float4*>(&Sb[4*k]);
            float4 sB = *reinterpret_cast<const float4*>(&Sb[4*k + 16]);
            a0 += Pa[4*k+0]*sA.x + Pb[4*k+0]*sB.x;
            a1 += Pa[4*k+1]*sA.y + Pb[4*k+1]*sB.y;
            a2 += Pa[4*k+2]*sA.z + Pb[4*k+2]*sB.z;
            a3 += Pa[4*k+3]*sA.w + Pb[4*k+3]*sB.w;
        });
        x = (a0 + a1) + (a2 + a3);
        float tv = x + u;
        z = fminf(fmaxf(tv, lb), ub);
        u = tv - z;
    }
    outg[gs * ND + l] = x;
}

extern "C" void kernel_launch(void* const* d_in, const int* in_sizes, int n_in,
                              void* d_out, int out_size, void* d_ws, size_t ws_size,
                              hipStream_t stream) {
    const float* A  = (const float*)d_in[0];
    const float* b  = (const float*)d_in[1];
    const float* c  = (const float*)d_in[2];
    const float* lb = (const float*)d_in[3];
    const float* ub = (const float*)d_in[4];
    float* out = (float*)d_out;
    const int B = in_sizes[1] / MD;                       // 32768 samples
    const size_t needP = (size_t)B * ND * ND * sizeof(float);   // 128 MiB
    const size_t needD = (size_t)B * ND * sizeof(float);        // 4 MiB
    if (ws_size >= needP + needD) {
        float* Pws = (float*)d_ws;
        float* dws = Pws + (size_t)B * ND * ND;
        precompute_kernel<<<B / SPA, 128, 0, stream>>>(A, b, c, Pws, dws);
        admm_iter_kernel<<<B / SPB3, 256, 0, stream>>>(Pws, dws, lb, ub, out);
    } else {
        admm_qp_kernel<<<B / SPB, 256, 0, stream>>>(A, b, c, lb, ub, out);
    }
}

// Round 17
// 176.482 us; speedup vs baseline: 1.1061x; 1.1061x over previous
//
#include <hip/hip_runtime.h>

typedef float f16v __attribute__((ext_vector_type(16)));
typedef float f4 __attribute__((ext_vector_type(4)));
typedef float f2 __attribute__((ext_vector_type(2)));

// static_for with FRONTEND-constant indices (SSA, no alloca) — see R6 notes.
template<int I> struct ic { static constexpr int v = I; };
template<int... I> struct iseq {};
template<int N, int... I> struct mk : mk<N-1, N-1, I...> {};
template<int... I> struct mk<0, I...> { using t = iseq<I...>; };
template<class F, int... I>
__device__ __forceinline__ void sfor_impl(F f, iseq<I...>) { (f(ic<I>{}), ...); }
template<int N, class F>
__device__ __forceinline__ void sfor(F f) { sfor_impl(f, typename mk<N>::t{}); }

namespace {
constexpr float kSigma  = 1.2f;    // 2*l2_reg + rho
constexpr float kJitter = 1e-5f;
constexpr int   kIters  = 100;
constexpr int   MD = 16;
constexpr int   ND = 32;
constexpr int   SPA = 8;     // samples per 128-thread block (16 lanes each)
constexpr int   AS  = 132;   // A sample stride in float4
constexpr int   MIS = 20;    // Minv row stride in floats
constexpr int   MSS = 324;   // Minv SAMPLE stride: 324%32==4 -> group base banks 4g;
                             // total LDS 16896+10368=27264B -> 6 blocks/CU (3 waves/SIMD)
}

__device__ __forceinline__ float4 lds_a4(const float* As, int r, int j) {
    return *reinterpret_cast<const float4*>(&As[r * 32 + ((j ^ (r & 7)) << 2)]);
}
__device__ __forceinline__ f2 lds_a2(const float* As, int r, int n) {
    return *reinterpret_cast<const f2*>(
        &As[r * 32 + ((((n >> 2) ^ (r & 7)) << 2) | (n & 3))]);
}

// ======================= Fused kernel: precompute + 100 ADMM iters =======================
// Phase 1 (LDS-bound): per 16-lane group, build P rows 2l,2l+1 and d in registers.
// Phase 2 (VALU-bound): iterate with s-exchange through the sample's dead Mi slot.
// Fusion wins: (a) no 128MiB P store+load; (b) waves/blocks in different phases
// overlap LDS-pipe and VALU work on the same CU (time ~ max, not sum).
__global__ void __launch_bounds__(128)
admm_fused_kernel(const float* __restrict__ Ag, const float* __restrict__ bg,
                  const float* __restrict__ cg, const float* __restrict__ lbg,
                  const float* __restrict__ ubg, float* __restrict__ outg)
{
    __shared__ __align__(16) float A_lds[SPA * AS * 4];   // 16896 B
    __shared__ __align__(16) float Mi_lds[SPA * MSS];     // 10368 B

    const int t = threadIdx.x;

    // ---- stage A for the block's 8 samples (coalesced, xor-swizzled f4)
    {
        const float4* src = reinterpret_cast<const float4*>(Ag) +
                            (size_t)blockIdx.x * (SPA * MD * ND / 4);
        float4* dst = reinterpret_cast<float4*>(A_lds);
        #pragma unroll
        for (int r = 0; r < 8; ++r) {
            int idx = r * 128 + t;
            int smp = idx >> 7;
            int row = (idx >> 3) & 15;
            int j   = idx & 7;
            dst[smp * AS + row * 8 + (j ^ (row & 7))] = src[idx];
        }
    }
    __syncthreads();   // only barrier: after this, each wave touches only its own samples

    const int lane = t & 63;
    const int l    = lane & 15;
    const int n0   = 2 * l;
    const int smp  = (t >> 6) * 4 + (lane >> 4);
    const size_t gs = (size_t)blockIdx.x * SPA + smp;
    const float* As = &A_lds[smp * AS * 4];
    float* Mi = &Mi_lds[smp * MSS];

    // ---- own A row into registers
    f16v Ar0, Ar1;
    sfor<4>([&](auto J) {
        constexpr int j = decltype(J)::v;
        float4 v  = lds_a4(As, l, j);
        Ar0[4*j+0] = v.x;  Ar0[4*j+1] = v.y;  Ar0[4*j+2] = v.z;  Ar0[4*j+3] = v.w;
        float4 w4 = lds_a4(As, l, j + 4);
        Ar1[4*j+0] = w4.x; Ar1[4*j+1] = w4.y; Ar1[4*j+2] = w4.z; Ar1[4*j+3] = w4.w;
    });

    // ---- M = A A^T + jitter*I (row l)
    f16v Mrow, Vrow;
    sfor<16>([&](auto K) {
        constexpr int k = decltype(K)::v;
        float a0 = 0.f, a1 = 0.f, a2 = 0.f, a3 = 0.f;
        sfor<4>([&](auto J) {
            constexpr int j = decltype(J)::v;
            float4 v  = lds_a4(As, k, j);
            a0 += Ar0[4*j+0]*v.x;  a1 += Ar0[4*j+1]*v.y;
            a2 += Ar0[4*j+2]*v.z;  a3 += Ar0[4*j+3]*v.w;
            float4 w4 = lds_a4(As, k, j + 4);
            a0 += Ar1[4*j+0]*w4.x; a1 += Ar1[4*j+1]*w4.y;
            a2 += Ar1[4*j+2]*w4.z; a3 += Ar1[4*j+3]*w4.w;
        });
        Mrow[k] = (a0+a1)+(a2+a3) + ((k == l) ? kJitter : 0.f);
        Vrow[k] = (k == l) ? 1.f : 0.f;
    });

    // ---- triangular Gauss-Jordan inverse (SPD), width-16 shuffles
    sfor<16>([&](auto K) {
        constexpr int k = decltype(K)::v;
        float ip = 1.f / __shfl(Mrow[k], k, 16);
        float f  = (l == k) ? 0.f : Mrow[k] * ip;
        sfor<16>([&](auto J) {
            constexpr int j = decltype(J)::v;
            if constexpr (j > k) {
                float mj = __shfl(Mrow[j], k, 16);
                Mrow[j] = (l == k) ? mj * ip : Mrow[j] - f * mj;
            }
        });
        sfor<16>([&](auto J) {
            constexpr int j = decltype(J)::v;
            if constexpr (j < k) {
                float vj = __shfl(Vrow[j], k, 16);
                Vrow[j] = (l == k) ? vj * ip : Vrow[j] - f * vj;
            }
        });
        Vrow[k] = (l == k) ? ip : -f;
    });

    // ---- w = Minv b
    float w = 0.f;
    {
        float bval = bg[gs * MD + l];
        sfor<16>([&](auto K) {
            constexpr int k = decltype(K)::v;
            w += Vrow[k] * __shfl(bval, k, 16);
        });
    }

    // ---- hand Minv to LDS (row l); Vrow dead after (same-wave handoff)
    sfor<4>([&](auto J) {
        constexpr int j = decltype(J)::v;
        *reinterpret_cast<float4*>(&Mi[l * MIS + 4*j]) =
            make_float4(Vrow[4*j+0], Vrow[4*j+1], Vrow[4*j+2], Vrow[4*j+3]);
    });
    asm volatile("s_waitcnt lgkmcnt(0)" ::: "memory");

    // ---- C rows n0,n0+1 of A^T Minv, fused with q = A^T w
    f16v Ca = (f16v)0.0f, Cb = (f16v)0.0f;
    float q0 = 0.f, q1 = 0.f;
    sfor<16>([&](auto K) {
        constexpr int k = decltype(K)::v;
        f2 ak = lds_a2(As, k, n0);
        float wm = __shfl(w, k, 16);
        q0 += ak[0] * wm;
        q1 += ak[1] * wm;
        sfor<4>([&](auto J) {
            constexpr int j = decltype(J)::v;
            float4 mv = *reinterpret_cast<const float4*>(&Mi[k * MIS + 4*j]);
            Ca[4*j+0] += ak[0]*mv.x; Ca[4*j+1] += ak[0]*mv.y;
            Ca[4*j+2] += ak[0]*mv.z; Ca[4*j+3] += ak[0]*mv.w;
            Cb[4*j+0] += ak[1]*mv.x; Cb[4*j+1] += ak[1]*mv.y;
            Cb[4*j+2] += ak[1]*mv.z; Cb[4*j+3] += ak[1]*mv.w;
        });
    });

    // ---- P rows n0,n0+1 = (I - C A)/sigma, kept in REGISTERS for the iter phase
    f16v P0a = (f16v)0.0f, P0b = (f16v)0.0f;   // row 2l:   cols 0-15 / 16-31
    f16v P1a = (f16v)0.0f, P1b = (f16v)0.0f;   // row 2l+1
    sfor<16>([&](auto M) {
        constexpr int m = decltype(M)::v;
        float c0 = Ca[m], c1 = Cb[m];
        sfor<4>([&](auto J) {
            constexpr int j = decltype(J)::v;
            float4 v  = lds_a4(As, m, j);
            P0a[4*j+0] += c0*v.x;  P0a[4*j+1] += c0*v.y;
            P0a[4*j+2] += c0*v.z;  P0a[4*j+3] += c0*v.w;
            P1a[4*j+0] += c1*v.x;  P1a[4*j+1] += c1*v.y;
            P1a[4*j+2] += c1*v.z;  P1a[4*j+3] += c1*v.w;
            float4 w4 = lds_a4(As, m, j + 4);
            P0b[4*j+0] += c0*w4.x; P0b[4*j+1] += c0*w4.y;
            P0b[4*j+2] += c0*w4.z; P0b[4*j+3] += c0*w4.w;
            P1b[4*j+0] += c1*w4.x; P1b[4*j+1] += c1*w4.y;
            P1b[4*j+2] += c1*w4.z; P1b[4*j+3] += c1*w4.w;
        });
    });
    constexpr float is = 1.f / kSigma;
    sfor<16>([&](auto N) {
        constexpr int n = decltype(N)::v;
        P0a[n] = (((n      == n0    ) ? 1.f : 0.f) - P0a[n]) * is;
        P0b[n] = (((n + 16 == n0    ) ? 1.f : 0.f) - P0b[n]) * is;
        P1a[n] = (((n      == n0 + 1) ? 1.f : 0.f) - P1a[n]) * is;
        P1b[n] = (((n + 16 == n0 + 1) ? 1.f : 0.f) - P1b[n]) * is;
    });

    // ---- d = q - P c (in registers)
    float d0, d1;
    {
        float cv0 = cg[gs * ND + l];
        float cv1 = cg[gs * ND + 16 + l];
        float pc0 = 0.f, pc1 = 0.f;
        sfor<16>([&](auto N) {
            constexpr int n = decltype(N)::v;
            float cn = __shfl(cv0, n, 16);
            pc0 += P0a[n] * cn;
            pc1 += P1a[n] * cn;
        });
        sfor<16>([&](auto N) {
            constexpr int n = decltype(N)::v;
            float cn = __shfl(cv1, n, 16);
            pc0 += P0b[n] * cn;
            pc1 += P1b[n] * cn;
        });
        d0 = q0 - pc0;
        d1 = q1 - pc1;
    }

    // ================= Phase 2: 100 ADMM iterations, P in registers =================
    // s-exchange through the sample's (now dead) Mi slot. Slot base banks 4g
    // per group -> uniform f4 reads hit 16 consecutive banks per wave: conflict-free.
    f2 lbv = *reinterpret_cast<const f2*>(lbg + gs * ND + n0);
    f2 ubv = *reinterpret_cast<const f2*>(ubg + gs * ND + n0);
    float lb0 = lbv[0], lb1 = lbv[1], ub0 = ubv[0], ub1 = ubv[1];
    float z0 = fminf(fmaxf(0.f, lb0), ub0);
    float z1 = fminf(fmaxf(0.f, lb1), ub1);
    float u0 = 0.f, u1 = 0.f, x0 = 0.f, x1 = 0.f;

    float* Sb = Mi;                                   // own sample's slot
    const f4* Sv = reinterpret_cast<const f4*>(Sb);
    for (int it = 0; it < kIters; ++it) {
        f2 sp; sp[0] = z0 - u0; sp[1] = z1 - u1;       // rho == 1
        *reinterpret_cast<f2*>(&Sb[n0]) = sp;          // slot holds s[0..31]
        asm volatile("s_waitcnt lgkmcnt(0)" ::: "memory");  // wave-synchronous exchange
        // 4 chains, 16 deep each: a0/a1 = row 2l, b0/b1 = row 2l+1
        float a0 = 0.f, a1 = 0.f, b0 = 0.f, b1 = 0.f;
        sfor<8>([&](auto Q) {
            constexpr int q = decltype(Q)::v;
            f4 S4 = Sv[q];                             // s[4q..4q+3], uniform per group
            if constexpr (q < 4) {
                constexpr int c = 4 * q;
                a0 = fmaf(P0a[c+0], S4[0], a0); a0 = fmaf(P0a[c+1], S4[1], a0);
                a1 = fmaf(P0a[c+2], S4[2], a1); a1 = fmaf(P0a[c+3], S4[3], a1);
                b0 = fmaf(P1a[c+0], S4[0], b0); b0 = fmaf(P1a[c+1], S4[1], b0);
                b1 = fmaf(P1a[c+2], S4[2], b1); b1 = fmaf(P1a[c+3], S4[3], b1);
            } else {
                constexpr int c = 4 * (q - 4);
                a0 = fmaf(P0b[c+0], S4[0], a0); a0 = fmaf(P0b[c+1], S4[1], a0);
                a1 = fmaf(P0b[c+2], S4[2], a1); a1 = fmaf(P0b[c+3], S4[3], a1);
                b0 = fmaf(P1b[c+0], S4[0], b0); b0 = fmaf(P1b[c+1], S4[1], b0);
                b1 = fmaf(P1b[c+2], S4[2], b1); b1 = fmaf(P1b[c+3], S4[3], b1);
            }
        });
        x0 = d0 + (a0 + a1);
        x1 = d1 + (b0 + b1);
        float t0 = x0 + u0, t1 = x1 + u1;
        z0 = fminf(fmaxf(t0, lb0), ub0);
        z1 = fminf(fmaxf(t1, lb1), ub1);
        u0 = t0 - z0;
        u1 = t1 - z1;
    }

    f2 xo; xo[0] = x0; xo[1] = x1;
    *reinterpret_cast<f2*>(outg + gs * ND + n0) = xo;
}

extern "C" void kernel_launch(void* const* d_in, const int* in_sizes, int n_in,
                              void* d_out, int out_size, void* d_ws, size_t ws_size,
                              hipStream_t stream) {
    const float* A  = (const float*)d_in[0];
    const float* b  = (const float*)d_in[1];
    const float* c  = (const float*)d_in[2];
    const float* lb = (const float*)d_in[3];
    const float* ub = (const float*)d_in[4];
    float* out = (float*)d_out;
    const int B = in_sizes[1] / MD;      // 32768 samples
    admm_fused_kernel<<<B / SPA, 128, 0, stream>>>(A, b, c, lb, ub, out);
}

// Round 18
// 170.153 us; speedup vs baseline: 1.1472x; 1.0372x over previous
//
#include <hip/hip_runtime.h>

typedef float f16v __attribute__((ext_vector_type(16)));
typedef float f4 __attribute__((ext_vector_type(4)));
typedef float f2 __attribute__((ext_vector_type(2)));

// static_for with FRONTEND-constant indices (SSA, no alloca) — see R6 notes.
template<int I> struct ic { static constexpr int v = I; };
template<int... I> struct iseq {};
template<int N, int... I> struct mk : mk<N-1, N-1, I...> {};
template<int... I> struct mk<0, I...> { using t = iseq<I...>; };
template<class F, int... I>
__device__ __forceinline__ void sfor_impl(F f, iseq<I...>) { (f(ic<I>{}), ...); }
template<int N, class F>
__device__ __forceinline__ void sfor(F f) { sfor_impl(f, typename mk<N>::t{}); }

namespace {
constexpr float kSigma  = 1.2f;    // 2*l2_reg + rho
constexpr float kJitter = 1e-5f;
constexpr int   kIters  = 100;
constexpr int   MD = 16;
constexpr int   ND = 32;
constexpr int   SPA = 8;     // samples per 128-thread block (16 lanes each)
constexpr int   AS  = 132;   // A sample stride in float4
constexpr int   MIS = 20;    // Minv row stride in floats
constexpr int   MSS = 324;   // Minv sample stride (group bases on distinct banks)
}

__device__ __forceinline__ float4 lds_a4(const float* As, int r, int j) {
    return *reinterpret_cast<const float4*>(&As[r * 32 + ((j ^ (r & 7)) << 2)]);
}
__device__ __forceinline__ f2 lds_a2(const float* As, int r, int n) {
    return *reinterpret_cast<const f2*>(
        &As[r * 32 + ((((n >> 2) ^ (r & 7)) << 2) | (n & 3))]);
}

// ============ Fused kernel: precompute P (ring order) + 100 LDS-free ADMM iters ============
// Phase 1: build P rows 2l,2l+1 in RING order: slot j = columns 2cp,2cp+1, cp=(l-j)&15.
// Phase 2: x = P s via 16-step DPP ring — v_fmac_f32_dpp fuses the lane rotation into
// the FMA (1 instr/term, zero movs, ZERO LDS, no barriers). Kills the 95us LDS-return
// floor that bounded every LDS-exchange iter variant (R10/R12/R15/R16/R17).
// row_ror:j semantics (lane l <- lane (l-j)&15) hardware-verified by R11's passing absmax.
__global__ void __launch_bounds__(128)
admm_fused_kernel(const float* __restrict__ Ag, const float* __restrict__ bg,
                  const float* __restrict__ cg, const float* __restrict__ lbg,
                  const float* __restrict__ ubg, float* __restrict__ outg)
{
    __shared__ __align__(16) float A_lds[SPA * AS * 4];   // 16896 B
    __shared__ __align__(16) float Mi_lds[SPA * MSS];     // 10368 B

    const int t = threadIdx.x;

    // ---- stage A for the block's 8 samples (coalesced, xor-swizzled f4)
    {
        const float4* src = reinterpret_cast<const float4*>(Ag) +
                            (size_t)blockIdx.x * (SPA * MD * ND / 4);
        float4* dst = reinterpret_cast<float4*>(A_lds);
        #pragma unroll
        for (int r = 0; r < 8; ++r) {
            int idx = r * 128 + t;
            int smp = idx >> 7;
            int row = (idx >> 3) & 15;
            int j   = idx & 7;
            dst[smp * AS + row * 8 + (j ^ (row & 7))] = src[idx];
        }
    }
    __syncthreads();   // only barrier in the kernel

    const int lane = t & 63;
    const int l    = lane & 15;
    const int n0   = 2 * l;
    const int smp  = (t >> 6) * 4 + (lane >> 4);
    const size_t gs = (size_t)blockIdx.x * SPA + smp;
    const float* As = &A_lds[smp * AS * 4];
    float* Mi = &Mi_lds[smp * MSS];

    // ---- own A row into registers
    f16v Ar0, Ar1;
    sfor<4>([&](auto J) {
        constexpr int j = decltype(J)::v;
        float4 v  = lds_a4(As, l, j);
        Ar0[4*j+0] = v.x;  Ar0[4*j+1] = v.y;  Ar0[4*j+2] = v.z;  Ar0[4*j+3] = v.w;
        float4 w4 = lds_a4(As, l, j + 4);
        Ar1[4*j+0] = w4.x; Ar1[4*j+1] = w4.y; Ar1[4*j+2] = w4.z; Ar1[4*j+3] = w4.w;
    });

    // ---- M = A A^T + jitter*I (row l)
    f16v Mrow, Vrow;
    sfor<16>([&](auto K) {
        constexpr int k = decltype(K)::v;
        float a0 = 0.f, a1 = 0.f, a2 = 0.f, a3 = 0.f;
        sfor<4>([&](auto J) {
            constexpr int j = decltype(J)::v;
            float4 v  = lds_a4(As, k, j);
            a0 += Ar0[4*j+0]*v.x;  a1 += Ar0[4*j+1]*v.y;
            a2 += Ar0[4*j+2]*v.z;  a3 += Ar0[4*j+3]*v.w;
            float4 w4 = lds_a4(As, k, j + 4);
            a0 += Ar1[4*j+0]*w4.x; a1 += Ar1[4*j+1]*w4.y;
            a2 += Ar1[4*j+2]*w4.z; a3 += Ar1[4*j+3]*w4.w;
        });
        Mrow[k] = (a0+a1)+(a2+a3) + ((k == l) ? kJitter : 0.f);
        Vrow[k] = (k == l) ? 1.f : 0.f;
    });

    // ---- triangular Gauss-Jordan inverse (SPD), width-16 shuffles
    sfor<16>([&](auto K) {
        constexpr int k = decltype(K)::v;
        float ip = 1.f / __shfl(Mrow[k], k, 16);
        float f  = (l == k) ? 0.f : Mrow[k] * ip;
        sfor<16>([&](auto J) {
            constexpr int j = decltype(J)::v;
            if constexpr (j > k) {
                float mj = __shfl(Mrow[j], k, 16);
                Mrow[j] = (l == k) ? mj * ip : Mrow[j] - f * mj;
            }
        });
        sfor<16>([&](auto J) {
            constexpr int j = decltype(J)::v;
            if constexpr (j < k) {
                float vj = __shfl(Vrow[j], k, 16);
                Vrow[j] = (l == k) ? vj * ip : Vrow[j] - f * vj;
            }
        });
        Vrow[k] = (l == k) ? ip : -f;
    });

    // ---- w = Minv b
    float w = 0.f;
    {
        float bval = bg[gs * MD + l];
        sfor<16>([&](auto K) {
            constexpr int k = decltype(K)::v;
            w += Vrow[k] * __shfl(bval, k, 16);
        });
    }

    // ---- hand Minv to LDS (row l); Vrow dead after (same-wave handoff)
    sfor<4>([&](auto J) {
        constexpr int j = decltype(J)::v;
        *reinterpret_cast<float4*>(&Mi[l * MIS + 4*j]) =
            make_float4(Vrow[4*j+0], Vrow[4*j+1], Vrow[4*j+2], Vrow[4*j+3]);
    });
    asm volatile("s_waitcnt lgkmcnt(0)" ::: "memory");

    // ---- C rows n0,n0+1 of A^T Minv, fused with q = A^T w
    f16v Ca = (f16v)0.0f, Cb = (f16v)0.0f;
    float q0 = 0.f, q1 = 0.f;
    sfor<16>([&](auto K) {
        constexpr int k = decltype(K)::v;
        f2 ak = lds_a2(As, k, n0);
        float wm = __shfl(w, k, 16);
        q0 += ak[0] * wm;
        q1 += ak[1] * wm;
        sfor<4>([&](auto J) {
            constexpr int j = decltype(J)::v;
            float4 mv = *reinterpret_cast<const float4*>(&Mi[k * MIS + 4*j]);
            Ca[4*j+0] += ak[0]*mv.x; Ca[4*j+1] += ak[0]*mv.y;
            Ca[4*j+2] += ak[0]*mv.z; Ca[4*j+3] += ak[0]*mv.w;
            Cb[4*j+0] += ak[1]*mv.x; Cb[4*j+1] += ak[1]*mv.y;
            Cb[4*j+2] += ak[1]*mv.z; Cb[4*j+3] += ak[1]*mv.w;
        });
    });

    // ---- P in RING order: Qa_j = (P[2l][2cp], P[2l][2cp+1]), Qb_j = row 2l+1; cp=(l-j)&15.
    // Identity lands only in slot 0 (cp==l): Qa0[0] += 1, Qb0[1] += 1.
    // Per-lane f2 A-reads: 16 lanes hit 16 distinct even pairs of a row -> conflict-free.
    constexpr float is = 1.f / kSigma;
#define QBUILD(j)                                                             \
    f2 Qa##j, Qb##j;                                                          \
    {                                                                         \
        const int n = 2 * ((l - (j)) & 15);                                   \
        float qa0 = 0.f, qa1 = 0.f, qb0 = 0.f, qb1 = 0.f;                     \
        sfor<16>([&](auto M) {                                                \
            constexpr int m = decltype(M)::v;                                 \
            f2 ak = lds_a2(As, m, n);                                         \
            qa0 = fmaf(Ca[m], ak[0], qa0); qa1 = fmaf(Ca[m], ak[1], qa1);     \
            qb0 = fmaf(Cb[m], ak[0], qb0); qb1 = fmaf(Cb[m], ak[1], qb1);     \
        });                                                                   \
        Qa##j[0] = ((((j) == 0) ? 1.f : 0.f) - qa0) * is;                     \
        Qa##j[1] = (0.f - qa1) * is;                                          \
        Qb##j[0] = (0.f - qb0) * is;                                          \
        Qb##j[1] = ((((j) == 0) ? 1.f : 0.f) - qb1) * is;                     \
    }
    QBUILD(0)  QBUILD(1)  QBUILD(2)  QBUILD(3)
    QBUILD(4)  QBUILD(5)  QBUILD(6)  QBUILD(7)
    QBUILD(8)  QBUILD(9)  QBUILD(10) QBUILD(11)
    QBUILD(12) QBUILD(13) QBUILD(14) QBUILD(15)
#undef QBUILD

    // ---- d = q - P c (ring order; one-time shuffles)
    float d0, d1;
    {
        f2 cpr = *reinterpret_cast<const f2*>(cg + gs * ND + n0);
        float pc0 = 0.f, pc1 = 0.f;
#define DSTEP(j) {                                                            \
        const int cp = (l - (j)) & 15;                                        \
        float c0 = __shfl(cpr[0], cp, 16);                                    \
        float c1 = __shfl(cpr[1], cp, 16);                                    \
        pc0 += Qa##j[0]*c0 + Qa##j[1]*c1;                                     \
        pc1 += Qb##j[0]*c0 + Qb##j[1]*c1; }
        DSTEP(0)  DSTEP(1)  DSTEP(2)  DSTEP(3)
        DSTEP(4)  DSTEP(5)  DSTEP(6)  DSTEP(7)
        DSTEP(8)  DSTEP(9)  DSTEP(10) DSTEP(11)
        DSTEP(12) DSTEP(13) DSTEP(14) DSTEP(15)
#undef DSTEP
        d0 = q0 - pc0;
        d1 = q1 - pc1;
    }

    // ================= Phase 2: 100 iterations, ZERO LDS, no barriers =================
    f2 lbv = *reinterpret_cast<const f2*>(lbg + gs * ND + n0);
    f2 ubv = *reinterpret_cast<const f2*>(ubg + gs * ND + n0);
    float lb0 = lbv[0], lb1 = lbv[1], ub0 = ubv[0], ub1 = ubv[1];
    float z0 = fminf(fmaxf(0.f, lb0), ub0);
    float z1 = fminf(fmaxf(0.f, lb1), ub1);
    float u0 = 0.f, u1 = 0.f, x0 = 0.f, x1 = 0.f;

    // acc += rotated(s) * q in ONE instruction: v_fmac_f32 with src0 DPP row_ror.
#define FSTEP(j)                                                              \
    asm("v_fmac_f32_dpp %0, %1, %2 row_ror:" #j " row_mask:0xf bank_mask:0xf" \
        : "+v"(ae) : "v"(s0), "v"(Qa##j[0]));                                 \
    asm("v_fmac_f32_dpp %0, %1, %2 row_ror:" #j " row_mask:0xf bank_mask:0xf" \
        : "+v"(ao) : "v"(s1), "v"(Qa##j[1]));                                 \
    asm("v_fmac_f32_dpp %0, %1, %2 row_ror:" #j " row_mask:0xf bank_mask:0xf" \
        : "+v"(be) : "v"(s0), "v"(Qb##j[0]));                                 \
    asm("v_fmac_f32_dpp %0, %1, %2 row_ror:" #j " row_mask:0xf bank_mask:0xf" \
        : "+v"(bo) : "v"(s1), "v"(Qb##j[1]));

    for (int it = 0; it < kIters; ++it) {
        float s0 = z0 - u0, s1 = z1 - u1;          // own column pair (rho == 1)
        float ae = d0, ao = 0.f, be = d1, bo = 0.f;
        // slot 0: s local, plain FMA
        ae = fmaf(Qa0[0], s0, ae); ao = fmaf(Qa0[1], s1, ao);
        be = fmaf(Qb0[0], s0, be); bo = fmaf(Qb0[1], s1, bo);
        FSTEP(1)  FSTEP(2)  FSTEP(3)  FSTEP(4)  FSTEP(5)
        FSTEP(6)  FSTEP(7)  FSTEP(8)  FSTEP(9)  FSTEP(10)
        FSTEP(11) FSTEP(12) FSTEP(13) FSTEP(14) FSTEP(15)
        x0 = ae + ao;
        x1 = be + bo;
        float t0 = x0 + u0, t1 = x1 + u1;
        z0 = fminf(fmaxf(t0, lb0), ub0);
        z1 = fminf(fmaxf(t1, lb1), ub1);
        u0 = t0 - z0;
        u1 = t1 - z1;
    }
#undef FSTEP

    f2 xo; xo[0] = x0; xo[1] = x1;
    *reinterpret_cast<f2*>(outg + gs * ND + n0) = xo;
}

extern "C" void kernel_launch(void* const* d_in, const int* in_sizes, int n_in,
                              void* d_out, int out_size, void* d_ws, size_t ws_size,
                              hipStream_t stream) {
    const float* A  = (const float*)d_in[0];
    const float* b  = (const float*)d_in[1];
    const float* c  = (const float*)d_in[2];
    const float* lb = (const float*)d_in[3];
    const float* ub = (const float*)d_in[4];
    float* out = (float*)d_out;
    const int B = in_sizes[1] / MD;      // 32768 samples
    admm_fused_kernel<<<B / SPA, 128, 0, stream>>>(A, b, c, lb, ub, out);
}

// Round 19
// 155.384 us; speedup vs baseline: 1.2563x; 1.0950x over previous
//
#include <hip/hip_runtime.h>

typedef float f16v __attribute__((ext_vector_type(16)));
typedef float f4 __attribute__((ext_vector_type(4)));
typedef float f2 __attribute__((ext_vector_type(2)));

// static_for with FRONTEND-constant indices (SSA, no alloca) — see R6 notes.
template<int I> struct ic { static constexpr int v = I; };
template<int... I> struct iseq {};
template<int N, int... I> struct mk : mk<N-1, N-1, I...> {};
template<int... I> struct mk<0, I...> { using t = iseq<I...>; };
template<class F, int... I>
__device__ __forceinline__ void sfor_impl(F f, iseq<I...>) { (f(ic<I>{}), ...); }
template<int N, class F>
__device__ __forceinline__ void sfor(F f) { sfor_impl(f, typename mk<N>::t{}); }

namespace {
constexpr float kSigma  = 1.2f;    // 2*l2_reg + rho
constexpr float kJitter = 1e-5f;
constexpr int   kIters  = 100;
constexpr int   MD = 16;
constexpr int   ND = 32;
constexpr int   SPA = 8;     // samples per 128-thread block (16 lanes each)
constexpr int   AS  = 132;   // A sample stride in float4
}

__device__ __forceinline__ float4 lds_a4(const float* As, int r, int j) {
    return *reinterpret_cast<const float4*>(&As[r * 32 + ((j ^ (r & 7)) << 2)]);
}
__device__ __forceinline__ f2 lds_a2(const float* As, int r, int n) {
    return *reinterpret_cast<const f2*>(
        &As[r * 32 + ((((n >> 2) ^ (r & 7)) << 2) | (n & 3))]);
}

// ============ Fused kernel: precompute P (ring order) + 100 LDS-free ADMM iters ============
// R18 structure with Mi_lds DELETED: the Minv hand-off (GJ -> C-build) now goes through
// width-16 shuffles on Vrow instead of an LDS buffer. Frees 10.4KB/block: LDS footprint
// 27648 -> 16896B, blocks/CU 6 -> 9, waves/CU 12 -> 18. R18 was VALU-bound at 84% busy
// with a ~16% occupancy-shaped idle bubble; this buys the residency to close it.
// Phase 2 unchanged: 16-step DPP ring (v_fmac_f32_dpp row_ror:j), zero LDS, no barriers.
__global__ void __launch_bounds__(128)
admm_fused_kernel(const float* __restrict__ Ag, const float* __restrict__ bg,
                  const float* __restrict__ cg, const float* __restrict__ lbg,
                  const float* __restrict__ ubg, float* __restrict__ outg)
{
    __shared__ __align__(16) float A_lds[SPA * AS * 4];   // 16896 B (only LDS)

    const int t = threadIdx.x;

    // ---- stage A for the block's 8 samples (coalesced, xor-swizzled f4)
    {
        const float4* src = reinterpret_cast<const float4*>(Ag) +
                            (size_t)blockIdx.x * (SPA * MD * ND / 4);
        float4* dst = reinterpret_cast<float4*>(A_lds);
        #pragma unroll
        for (int r = 0; r < 8; ++r) {
            int idx = r * 128 + t;
            int smp = idx >> 7;
            int row = (idx >> 3) & 15;
            int j   = idx & 7;
            dst[smp * AS + row * 8 + (j ^ (row & 7))] = src[idx];
        }
    }
    __syncthreads();   // only barrier in the kernel

    const int lane = t & 63;
    const int l    = lane & 15;
    const int n0   = 2 * l;
    const int smp  = (t >> 6) * 4 + (lane >> 4);
    const size_t gs = (size_t)blockIdx.x * SPA + smp;
    const float* As = &A_lds[smp * AS * 4];

    // ---- own A row into registers
    f16v Ar0, Ar1;
    sfor<4>([&](auto J) {
        constexpr int j = decltype(J)::v;
        float4 v  = lds_a4(As, l, j);
        Ar0[4*j+0] = v.x;  Ar0[4*j+1] = v.y;  Ar0[4*j+2] = v.z;  Ar0[4*j+3] = v.w;
        float4 w4 = lds_a4(As, l, j + 4);
        Ar1[4*j+0] = w4.x; Ar1[4*j+1] = w4.y; Ar1[4*j+2] = w4.z; Ar1[4*j+3] = w4.w;
    });

    // ---- M = A A^T + jitter*I (row l)
    f16v Mrow, Vrow;
    sfor<16>([&](auto K) {
        constexpr int k = decltype(K)::v;
        float a0 = 0.f, a1 = 0.f, a2 = 0.f, a3 = 0.f;
        sfor<4>([&](auto J) {
            constexpr int j = decltype(J)::v;
            float4 v  = lds_a4(As, k, j);
            a0 += Ar0[4*j+0]*v.x;  a1 += Ar0[4*j+1]*v.y;
            a2 += Ar0[4*j+2]*v.z;  a3 += Ar0[4*j+3]*v.w;
            float4 w4 = lds_a4(As, k, j + 4);
            a0 += Ar1[4*j+0]*w4.x; a1 += Ar1[4*j+1]*w4.y;
            a2 += Ar1[4*j+2]*w4.z; a3 += Ar1[4*j+3]*w4.w;
        });
        Mrow[k] = (a0+a1)+(a2+a3) + ((k == l) ? kJitter : 0.f);
        Vrow[k] = (k == l) ? 1.f : 0.f;
    });

    // ---- triangular Gauss-Jordan inverse (SPD), width-16 shuffles
    sfor<16>([&](auto K) {
        constexpr int k = decltype(K)::v;
        float ip = 1.f / __shfl(Mrow[k], k, 16);
        float f  = (l == k) ? 0.f : Mrow[k] * ip;
        sfor<16>([&](auto J) {
            constexpr int j = decltype(J)::v;
            if constexpr (j > k) {
                float mj = __shfl(Mrow[j], k, 16);
                Mrow[j] = (l == k) ? mj * ip : Mrow[j] - f * mj;
            }
        });
        sfor<16>([&](auto J) {
            constexpr int j = decltype(J)::v;
            if constexpr (j < k) {
                float vj = __shfl(Vrow[j], k, 16);
                Vrow[j] = (l == k) ? vj * ip : Vrow[j] - f * vj;
            }
        });
        Vrow[k] = (l == k) ? ip : -f;
    });

    // ---- w = Minv b
    float w = 0.f;
    {
        float bval = bg[gs * MD + l];
        sfor<16>([&](auto K) {
            constexpr int k = decltype(K)::v;
            w += Vrow[k] * __shfl(bval, k, 16);
        });
    }

    // ---- C rows n0,n0+1 of A^T Minv via Vrow shuffles (no LDS buffer), fused with q = A^T w
    f16v Ca = (f16v)0.0f, Cb = (f16v)0.0f;
    float q0 = 0.f, q1 = 0.f;
    sfor<16>([&](auto K) {
        constexpr int k = decltype(K)::v;
        f2 ak = lds_a2(As, k, n0);
        float wm = __shfl(w, k, 16);
        q0 = fmaf(ak[0], wm, q0);
        q1 = fmaf(ak[1], wm, q1);
        sfor<16>([&](auto M) {
            constexpr int m = decltype(M)::v;
            float mv = __shfl(Vrow[m], k, 16);   // Minv[k][m]
            Ca[m] = fmaf(ak[0], mv, Ca[m]);
            Cb[m] = fmaf(ak[1], mv, Cb[m]);
        });
    });

    // ---- P in RING order: Qa_j = (P[2l][2cp], P[2l][2cp+1]), Qb_j = row 2l+1; cp=(l-j)&15.
    // Identity lands only in slot 0 (cp==l): Qa0[0] += 1, Qb0[1] += 1.
    constexpr float is = 1.f / kSigma;
#define QBUILD(j)                                                             \
    f2 Qa##j, Qb##j;                                                          \
    {                                                                         \
        const int n = 2 * ((l - (j)) & 15);                                   \
        float qa0 = 0.f, qa1 = 0.f, qb0 = 0.f, qb1 = 0.f;                     \
        sfor<16>([&](auto M) {                                                \
            constexpr int m = decltype(M)::v;                                 \
            f2 ak = lds_a2(As, m, n);                                         \
            qa0 = fmaf(Ca[m], ak[0], qa0); qa1 = fmaf(Ca[m], ak[1], qa1);     \
            qb0 = fmaf(Cb[m], ak[0], qb0); qb1 = fmaf(Cb[m], ak[1], qb1);     \
        });                                                                   \
        Qa##j[0] = ((((j) == 0) ? 1.f : 0.f) - qa0) * is;                     \
        Qa##j[1] = (0.f - qa1) * is;                                          \
        Qb##j[0] = (0.f - qb0) * is;                                          \
        Qb##j[1] = ((((j) == 0) ? 1.f : 0.f) - qb1) * is;                     \
    }
    QBUILD(0)  QBUILD(1)  QBUILD(2)  QBUILD(3)
    QBUILD(4)  QBUILD(5)  QBUILD(6)  QBUILD(7)
    QBUILD(8)  QBUILD(9)  QBUILD(10) QBUILD(11)
    QBUILD(12) QBUILD(13) QBUILD(14) QBUILD(15)
#undef QBUILD

    // ---- d = q - P c (ring order; one-time shuffles)
    float d0, d1;
    {
        f2 cpr = *reinterpret_cast<const f2*>(cg + gs * ND + n0);
        float pc0 = 0.f, pc1 = 0.f;
#define DSTEP(j) {                                                            \
        const int cp = (l - (j)) & 15;                                        \
        float c0 = __shfl(cpr[0], cp, 16);                                    \
        float c1 = __shfl(cpr[1], cp, 16);                                    \
        pc0 += Qa##j[0]*c0 + Qa##j[1]*c1;                                     \
        pc1 += Qb##j[0]*c0 + Qb##j[1]*c1; }
        DSTEP(0)  DSTEP(1)  DSTEP(2)  DSTEP(3)
        DSTEP(4)  DSTEP(5)  DSTEP(6)  DSTEP(7)
        DSTEP(8)  DSTEP(9)  DSTEP(10) DSTEP(11)
        DSTEP(12) DSTEP(13) DSTEP(14) DSTEP(15)
#undef DSTEP
        d0 = q0 - pc0;
        d1 = q1 - pc1;
    }

    // ================= Phase 2: 100 iterations, ZERO LDS, no barriers =================
    f2 lbv = *reinterpret_cast<const f2*>(lbg + gs * ND + n0);
    f2 ubv = *reinterpret_cast<const f2*>(ubg + gs * ND + n0);
    float lb0 = lbv[0], lb1 = lbv[1], ub0 = ubv[0], ub1 = ubv[1];
    float z0 = fminf(fmaxf(0.f, lb0), ub0);
    float z1 = fminf(fmaxf(0.f, lb1), ub1);
    float u0 = 0.f, u1 = 0.f, x0 = 0.f, x1 = 0.f;

    // acc += rotated(s) * q in ONE instruction: v_fmac_f32 with src0 DPP row_ror.
#define FSTEP(j)                                                              \
    asm("v_fmac_f32_dpp %0, %1, %2 row_ror:" #j " row_mask:0xf bank_mask:0xf" \
        : "+v"(ae) : "v"(s0), "v"(Qa##j[0]));                                 \
    asm("v_fmac_f32_dpp %0, %1, %2 row_ror:" #j " row_mask:0xf bank_mask:0xf" \
        : "+v"(ao) : "v"(s1), "v"(Qa##j[1]));                                 \
    asm("v_fmac_f32_dpp %0, %1, %2 row_ror:" #j " row_mask:0xf bank_mask:0xf" \
        : "+v"(be) : "v"(s0), "v"(Qb##j[0]));                                 \
    asm("v_fmac_f32_dpp %0, %1, %2 row_ror:" #j " row_mask:0xf bank_mask:0xf" \
        : "+v"(bo) : "v"(s1), "v"(Qb##j[1]));

    for (int it = 0; it < kIters; ++it) {
        float s0 = z0 - u0, s1 = z1 - u1;          // own column pair (rho == 1)
        float ae = d0, ao = 0.f, be = d1, bo = 0.f;
        // slot 0: s local, plain FMA
        ae = fmaf(Qa0[0], s0, ae); ao = fmaf(Qa0[1], s1, ao);
        be = fmaf(Qb0[0], s0, be); bo = fmaf(Qb0[1], s1, bo);
        FSTEP(1)  FSTEP(2)  FSTEP(3)  FSTEP(4)  FSTEP(5)
        FSTEP(6)  FSTEP(7)  FSTEP(8)  FSTEP(9)  FSTEP(10)
        FSTEP(11) FSTEP(12) FSTEP(13) FSTEP(14) FSTEP(15)
        x0 = ae + ao;
        x1 = be + bo;
        float t0 = x0 + u0, t1 = x1 + u1;
        z0 = fminf(fmaxf(t0, lb0), ub0);
        z1 = fminf(fmaxf(t1, lb1), ub1);
        u0 = t0 - z0;
        u1 = t1 - z1;
    }
#undef FSTEP

    f2 xo; xo[0] = x0; xo[1] = x1;
    *reinterpret_cast<f2*>(outg + gs * ND + n0) = xo;
}

extern "C" void kernel_launch(void* const* d_in, const int* in_sizes, int n_in,
                              void* d_out, int out_size, void* d_ws, size_t ws_size,
                              hipStream_t stream) {
    const float* A  = (const float*)d_in[0];
    const float* b  = (const float*)d_in[1];
    const float* c  = (const float*)d_in[2];
    const float* lb = (const float*)d_in[3];
    const float* ub = (const float*)d_in[4];
    float* out = (float*)d_out;
    const int B = in_sizes[1] / MD;      // 32768 samples
    admm_fused_kernel<<<B / SPA, 128, 0, stream>>>(A, b, c, lb, ub, out);
}